// Round 1
// 393.945 us; speedup vs baseline: 1.2467x; 1.2467x over previous
//
#include <hip/hip_runtime.h>

// Problem constants (fixed by reference)
constexpr int N_NEURONS  = 131072;
constexpr int X_ELEMS    = 4 * 131072 * 32;   // 16,777,216
constexpr int X4         = X_ELEMS / 4;       // 4,194,304 float4
constexpr int STATES_OFF = X_ELEMS;           // states start after x in d_out

// Fast tanh: t = 1 - 2/(e^{2|x|}+1), sign restored. Overflow-clean.
// Abs error ~1e-6 vs libm; passed all prior rounds.
__device__ __forceinline__ float fast_tanh(float x) {
  float a = fabsf(x);
  float e = __expf(2.0f * a);
  float t = 1.0f - __fdividef(2.0f, e + 1.0f);
  return copysignf(t, x);
}

__global__ __launch_bounds__(256) void tanh4_kernel(const float* __restrict__ x,
                                                    float* __restrict__ out) {
  int idx = blockIdx.x * 256 + threadIdx.x;
  float4 v = reinterpret_cast<const float4*>(x)[idx];
  #pragma unroll
  for (int k = 0; k < 4; ++k) {
    v.x = fast_tanh(v.x);
    v.y = fast_tanh(v.y);
    v.z = fast_tanh(v.z);
    v.w = fast_tanh(v.w);
  }
  reinterpret_cast<float4*>(out)[idx] = v;
}

// ---------------------------------------------------------------------------
// States path, rebuilt for R5.
//
// R4 post-mortem: 4-lane fp64 kernel was SPILL-bound, not compute-bound.
// FETCH 668MB / WRITE 368MB vs 33MB ideal (30x over-fetch = scratch traffic),
// VGPR=256, VALUBusy 15%. Root cause: 128 distinct LDS weight reads per layer
// get hoisted by hipcc into ~128 live doubles -> blows any cap -> spill.
//
// R5 design: ONE neuron per thread.
//  * Weights are wave-uniform -> compiler scalarizes to s_load -> SGPRs.
//    SGPRs are capped (~102) so prefetch hoisting CANNOT blow the VGPR file,
//    and s[pair] feeds v_fma_f64 directly (1 scalar operand allowed).
//  * No LDS at all (bank conflicts 1.2e7 -> 0), no cross-lane butterflies,
//    top-k fully lane-local.
//  * Weights pre-converted fp32->fp64 ONCE by a tiny setup kernel into
//    __device__ globals (rolled layer loop would otherwise pay 4096
//    v_cvt_f64_f32 per thread).
//  * Peak live VGPR state: ws[32]+s[32]+h[16]+top[8] ~ 190 regs.
//    Grid = 2048 waves = 8 waves/CU: exactly one occupancy round at <=256.
// ---------------------------------------------------------------------------

__device__ double g_wenc[16 * 32];   // [c][k] row-major, as given
__device__ double g_wdec[32 * 16];   // [state][c] row-major, as given
__device__ double g_benc[16];
__device__ double g_bdec[32];

__global__ __launch_bounds__(256) void convert_weights_kernel(
    const float* __restrict__ Wenc, const float* __restrict__ benc,
    const float* __restrict__ Wdec, const float* __restrict__ bdec) {
  const int t = threadIdx.x;
  #pragma unroll
  for (int i = t; i < 512; i += 256) {
    g_wenc[i] = (double)Wenc[i];
    g_wdec[i] = (double)Wdec[i];
  }
  if (t < 16)              g_benc[t]      = (double)benc[t];
  if (t >= 64 && t < 96)   g_bdec[t - 64] = (double)bdec[t - 64];
}

__global__ __launch_bounds__(256, 2) void enn_states_scalar_kernel(
    const float* __restrict__ ns, float* __restrict__ out) {
  const int n = blockIdx.x * 256 + threadIdx.x;   // one neuron per thread

  double s[32], ws[32];
  const float4* src = reinterpret_cast<const float4*>(ns) + (size_t)n * 8;
  #pragma unroll
  for (int j = 0; j < 8; ++j) {
    float4 v = src[j];
    s[4 * j + 0] = (double)v.x; s[4 * j + 1] = (double)v.y;
    s[4 * j + 2] = (double)v.z; s[4 * j + 3] = (double)v.w;
  }
  #pragma unroll
  for (int i = 0; i < 32; ++i) ws[i] = 0.0;

  double nrm = 0.0;
  #pragma unroll 1   // rolled: layer body ~2k inst (~16KB) fits I-cache
  for (int layer = 0; layer < 4; ++layer) {
    nrm = nrm * 0.7 + 1.0;            // w.sum(): 1, 1.7, 2.19, 2.533
    const double inv = 1.0 / nrm;

    // sparsity (|s|>=0.01), decay *0.9, recency recurrence, normalize.
    // st (= ws*inv) overwrites s[] -- s is dead until rec is produced.
    #pragma unroll
    for (int k = 0; k < 32; ++k) {
      double v = s[k];
      v = (fabs(v) >= 0.01) ? v : 0.0;
      double w = ws[k] * 0.7 + v * 0.9;
      ws[k] = w;
      s[k] = w * inv;
    }

    // h = relu(st @ Wenc^T + benc). Weights come in as SGPRs (uniform).
    double h[16];
    #pragma unroll
    for (int c = 0; c < 16; ++c) h[c] = g_benc[c];
    #pragma unroll
    for (int c = 0; c < 16; ++c) {
      #pragma unroll
      for (int k = 0; k < 32; ++k)
        h[c] = fma(s[k], g_wenc[c * 32 + k], h[c]);
    }
    #pragma unroll
    for (int c = 0; c < 16; ++c) h[c] = fmax(h[c], 0.0);

    // Decoder fused with importance threshold AND top-8 ladder insertion:
    // rec[i] = h . Wdec[i][:] + bdec[i]; threshold 0.05; insert |rec| into
    // a sorted-descending ladder of 8. All per-lane, no shuffles.
    double top[8];
    #pragma unroll
    for (int k = 0; k < 8; ++k) top[k] = 0.0;
    #pragma unroll
    for (int i = 0; i < 32; ++i) {
      double acc = g_bdec[i];
      #pragma unroll
      for (int c = 0; c < 16; ++c)
        acc = fma(h[c], g_wdec[i * 16 + c], acc);
      double r = (fabs(acc) >= 0.05) ? acc : 0.0;
      s[i] = r;
      double v = fabs(r);
      #pragma unroll
      for (int k = 0; k < 8; ++k) {
        double hi = fmax(top[k], v);
        v = fmin(top[k], v);
        top[k] = hi;
      }
    }
    const double kth = top[7];        // 8th largest of 32 (0 if <8 nonzero)
    #pragma unroll
    for (int i = 0; i < 32; ++i)
      s[i] = (fabs(s[i]) >= kth) ? s[i] : 0.0;
  }

  float4* dst = reinterpret_cast<float4*>(out + STATES_OFF) + (size_t)n * 8;
  #pragma unroll
  for (int j = 0; j < 8; ++j)
    dst[j] = make_float4((float)s[4 * j + 0], (float)s[4 * j + 1],
                         (float)s[4 * j + 2], (float)s[4 * j + 3]);
}

extern "C" void kernel_launch(void* const* d_in, const int* in_sizes, int n_in,
                              void* d_out, int out_size, void* d_ws, size_t ws_size,
                              hipStream_t stream) {
  const float* x    = (const float*)d_in[0];
  const float* ns   = (const float*)d_in[1];
  const float* Wenc = (const float*)d_in[2];
  const float* benc = (const float*)d_in[3];
  const float* Wdec = (const float*)d_in[4];
  const float* bdec = (const float*)d_in[5];
  float* out = (float*)d_out;

  convert_weights_kernel<<<1, 256, 0, stream>>>(Wenc, benc, Wdec, bdec);
  enn_states_scalar_kernel<<<N_NEURONS / 256, 256, 0, stream>>>(ns, out);
  tanh4_kernel<<<X4 / 256, 256, 0, stream>>>(x, out);
}

// Round 2
// 346.953 us; speedup vs baseline: 1.4156x; 1.1354x over previous
//
#include <hip/hip_runtime.h>

// Problem constants (fixed by reference)
constexpr int N_NEURONS  = 131072;
constexpr int X_ELEMS    = 4 * 131072 * 32;   // 16,777,216
constexpr int X4         = X_ELEMS / 4;       // 4,194,304 float4
constexpr int STATES_OFF = X_ELEMS;           // states start after x in d_out

// Fast tanh: t = 1 - 2/(e^{2|x|}+1), sign restored. Overflow-clean.
// Abs error ~1e-6 vs libm; passed all prior rounds.
__device__ __forceinline__ float fast_tanh(float x) {
  float a = fabsf(x);
  float e = __expf(2.0f * a);
  float t = 1.0f - __fdividef(2.0f, e + 1.0f);
  return copysignf(t, x);
}

__global__ __launch_bounds__(256) void tanh4_kernel(const float* __restrict__ x,
                                                    float* __restrict__ out) {
  int idx = blockIdx.x * 256 + threadIdx.x;
  float4 v = reinterpret_cast<const float4*>(x)[idx];
  #pragma unroll
  for (int k = 0; k < 4; ++k) {
    v.x = fast_tanh(v.x);
    v.y = fast_tanh(v.y);
    v.z = fast_tanh(v.z);
    v.w = fast_tanh(v.w);
  }
  reinterpret_cast<float4*>(out)[idx] = v;
}

// ---------------------------------------------------------------------------
// States path R6.
//
// R5 post-mortem: scalarization WORKED (SGPR=112, LDS=0, FETCH 668->18.5MB)
// but the register allocator chose a 104-VGPR budget -- below the 128 VGPRs
// needed just for s[32]+ws[32] -- and spilled ~34 doubles/thread to scratch
// (WRITE 35.3MB vs 16.9MB ideal). It bought 4-waves/SIMD occupancy that our
// fixed 2048-wave grid can never use, paying scratch latency at 2 waves/SIMD.
//
// R6: amdgpu_waves_per_eu(2,2) pins the allocator to the occupancy we
// actually launch -> 256-VGPR budget -> peak live set (~200) fits, no
// scratch. Structure unchanged: 1 neuron/thread keeps every weight address
// wave-uniform -> s_load into SGPRs (any lane-split makes weight addresses
// lane-divergent and kills scalarization; that was R4's failure).
// Minor: 1/nrm folded into the h epilogue (16 muls) instead of
// normalizing all 32 states (32 muls); s[] now holds raw ws recurrence.
// ---------------------------------------------------------------------------

__device__ double g_wenc[16 * 32];   // [c][k] row-major, as given
__device__ double g_wdec[32 * 16];   // [state][c] row-major, as given
__device__ double g_benc[16];
__device__ double g_bdec[32];

__global__ __launch_bounds__(256) void convert_weights_kernel(
    const float* __restrict__ Wenc, const float* __restrict__ benc,
    const float* __restrict__ Wdec, const float* __restrict__ bdec) {
  const int t = threadIdx.x;
  #pragma unroll
  for (int i = t; i < 512; i += 256) {
    g_wenc[i] = (double)Wenc[i];
    g_wdec[i] = (double)Wdec[i];
  }
  if (t < 16)              g_benc[t]      = (double)benc[t];
  if (t >= 64 && t < 96)   g_bdec[t - 64] = (double)bdec[t - 64];
}

__global__ __launch_bounds__(256)
__attribute__((amdgpu_waves_per_eu(2, 2)))
void enn_states_scalar_kernel(
    const float* __restrict__ ns, float* __restrict__ out) {
  const int n = blockIdx.x * 256 + threadIdx.x;   // one neuron per thread

  double s[32], ws[32];
  const float4* src = reinterpret_cast<const float4*>(ns) + (size_t)n * 8;
  #pragma unroll
  for (int j = 0; j < 8; ++j) {
    float4 v = src[j];
    s[4 * j + 0] = (double)v.x; s[4 * j + 1] = (double)v.y;
    s[4 * j + 2] = (double)v.z; s[4 * j + 3] = (double)v.w;
  }
  #pragma unroll
  for (int i = 0; i < 32; ++i) ws[i] = 0.0;

  double nrm = 0.0;
  #pragma unroll 1   // rolled: layer body ~2k inst fits I-cache
  for (int layer = 0; layer < 4; ++layer) {
    nrm = nrm * 0.7 + 1.0;            // w.sum(): 1, 1.7, 2.19, 2.533
    const double inv = 1.0 / nrm;

    // sparsity (|s|>=0.01), decay *0.9, recency recurrence.
    // ws[] holds the UN-normalized recurrence; 1/nrm is folded into the
    // encoder epilogue below (16 muls instead of 32).
    #pragma unroll
    for (int k = 0; k < 32; ++k) {
      double v = s[k];
      v = (fabs(v) >= 0.01) ? v : 0.0;
      ws[k] = ws[k] * 0.7 + v * 0.9;
    }

    // h = relu((ws*inv) @ Wenc^T + benc). Weights are wave-uniform ->
    // SGPRs; 16 independent fma chains per k step give the ILP that
    // covers f64 latency at 2 waves/SIMD.
    double h[16];
    #pragma unroll
    for (int c = 0; c < 16; ++c) h[c] = 0.0;
    #pragma unroll
    for (int k = 0; k < 32; ++k) {
      double wk = ws[k];
      #pragma unroll
      for (int c = 0; c < 16; ++c)
        h[c] = fma(wk, g_wenc[c * 32 + k], h[c]);
    }
    #pragma unroll
    for (int c = 0; c < 16; ++c)
      h[c] = fmax(fma(h[c], inv, g_benc[c]), 0.0);

    // Decoder fused with importance threshold AND top-8 ladder insertion.
    double top[8];
    #pragma unroll
    for (int k = 0; k < 8; ++k) top[k] = 0.0;
    #pragma unroll
    for (int i = 0; i < 32; ++i) {
      double acc = g_bdec[i];
      #pragma unroll
      for (int c = 0; c < 16; ++c)
        acc = fma(h[c], g_wdec[i * 16 + c], acc);
      double r = (fabs(acc) >= 0.05) ? acc : 0.0;
      s[i] = r;
      double v = fabs(r);
      #pragma unroll
      for (int k = 0; k < 8; ++k) {
        double hi = fmax(top[k], v);
        v = fmin(top[k], v);
        top[k] = hi;
      }
    }
    const double kth = top[7];        // 8th largest of 32 (0 if <8 nonzero)
    #pragma unroll
    for (int i = 0; i < 32; ++i)
      s[i] = (fabs(s[i]) >= kth) ? s[i] : 0.0;
  }

  float4* dst = reinterpret_cast<float4*>(out + STATES_OFF) + (size_t)n * 8;
  #pragma unroll
  for (int j = 0; j < 8; ++j)
    dst[j] = make_float4((float)s[4 * j + 0], (float)s[4 * j + 1],
                         (float)s[4 * j + 2], (float)s[4 * j + 3]);
}

extern "C" void kernel_launch(void* const* d_in, const int* in_sizes, int n_in,
                              void* d_out, int out_size, void* d_ws, size_t ws_size,
                              hipStream_t stream) {
  const float* x    = (const float*)d_in[0];
  const float* ns   = (const float*)d_in[1];
  const float* Wenc = (const float*)d_in[2];
  const float* benc = (const float*)d_in[3];
  const float* Wdec = (const float*)d_in[4];
  const float* bdec = (const float*)d_in[5];
  float* out = (float*)d_out;

  convert_weights_kernel<<<1, 256, 0, stream>>>(Wenc, benc, Wdec, bdec);
  enn_states_scalar_kernel<<<N_NEURONS / 256, 256, 0, stream>>>(ns, out);
  tanh4_kernel<<<X4 / 256, 256, 0, stream>>>(x, out);
}

// Round 4
// 277.864 us; speedup vs baseline: 1.7676x; 1.2486x over previous
//
#include <hip/hip_runtime.h>

// Problem constants (fixed by reference)
constexpr int N_NEURONS  = 131072;
constexpr int X_ELEMS    = 4 * 131072 * 32;   // 16,777,216
constexpr int X4         = X_ELEMS / 4;       // 4,194,304 float4
constexpr int STATES_OFF = X_ELEMS;           // states start after x in d_out

// Fast tanh: t = 1 - 2/(e^{2|x|}+1), sign restored. Overflow-clean.
// Abs error ~1e-6 vs libm; passed all prior rounds.
__device__ __forceinline__ float fast_tanh(float x) {
  float a = fabsf(x);
  float e = __expf(2.0f * a);
  float t = 1.0f - __fdividef(2.0f, e + 1.0f);
  return copysignf(t, x);
}

__global__ __launch_bounds__(256) void tanh4_kernel(const float* __restrict__ x,
                                                    float* __restrict__ out) {
  int idx = blockIdx.x * 256 + threadIdx.x;
  float4 v = reinterpret_cast<const float4*>(x)[idx];
  #pragma unroll
  for (int k = 0; k < 4; ++k) {
    v.x = fast_tanh(v.x);
    v.y = fast_tanh(v.y);
    v.z = fast_tanh(v.z);
    v.w = fast_tanh(v.w);
  }
  reinterpret_cast<float4*>(out)[idx] = v;
}

// ---------------------------------------------------------------------------
// States path R8.
//
// R7 post-mortem: f32 storage FAILED (absmax 0.205) -- the harness np
// reference is f64; every threshold compare and carried value must be f64
// (R6's all-f64 pipeline matched to bf16 quantum). Precision is pinned.
//
// R6 residual: allocator stuck at 104 VGPR (ignores waves_per_eu), spilling
// ~16 doubles/thread (WRITE 2x ideal). The budget comes from the backend's
// occupancy model -- so change the model's INPUTS instead of fighting it:
//   * s[32] (f64, decoder out -> next-layer in) moves to a 64KB LDS array
//     [state][tid]. That (a) removes 64 VGPRs of pressure and (b) caps
//     occupancy at 2 blocks/CU == what our 512-block grid gives anyway,
//     which raises the backend's VGPR budget to the 256 tier. No
//     __syncthreads needed: each thread touches only its own column.
//   * top-k filter deferred into next layer's threshold, IN F64:
//     keep iff |r| >= max(kth, 0.01) -- exactly the reference's two
//     sequential f64 compares (zeros stay zero). One 32-wide pass saved.
//   * Weights stay wave-uniform f64 in SGPRs (1 neuron/thread).
// Live set: ws[32]d(64) + hd[16]d(32) + top[8]d(16) + temps ~ 140 << 256.
// ---------------------------------------------------------------------------

__device__ double g_wenc[16 * 32];   // [c][k] row-major, as given
__device__ double g_wdec[32 * 16];   // [state][c] row-major, as given
__device__ double g_benc[16];
__device__ double g_bdec[32];

__global__ __launch_bounds__(256) void convert_weights_kernel(
    const float* __restrict__ Wenc, const float* __restrict__ benc,
    const float* __restrict__ Wdec, const float* __restrict__ bdec) {
  const int t = threadIdx.x;
  #pragma unroll
  for (int i = t; i < 512; i += 256) {
    g_wenc[i] = (double)Wenc[i];
    g_wdec[i] = (double)Wdec[i];
  }
  if (t < 16)              g_benc[t]      = (double)benc[t];
  if (t >= 64 && t < 96)   g_bdec[t - 64] = (double)bdec[t - 64];
}

__global__ __launch_bounds__(256)
__attribute__((amdgpu_waves_per_eu(2, 2)))
void enn_states_kernel(const float* __restrict__ ns, float* __restrict__ out) {
  // 32 states x 256 threads, f64: exactly 64 KB. Column-per-thread layout:
  // a wave's b64 access is 64 consecutive doubles -> full LDS throughput.
  __shared__ double s_lds[32][256];

  const int tid = threadIdx.x;
  const int n   = blockIdx.x * 256 + tid;   // one neuron per thread

  const float4* src = reinterpret_cast<const float4*>(ns) + (size_t)n * 8;
  #pragma unroll
  for (int j = 0; j < 8; ++j) {
    float4 v = src[j];
    s_lds[4 * j + 0][tid] = (double)v.x;
    s_lds[4 * j + 1][tid] = (double)v.y;
    s_lds[4 * j + 2][tid] = (double)v.z;
    s_lds[4 * j + 3][tid] = (double)v.w;
  }

  double ws[32];
  #pragma unroll
  for (int i = 0; i < 32; ++i) ws[i] = 0.0;

  double nrm = 0.0;
  double thr = 0.01;    // layer-0: sparsity only (deferred kth = 0)
  double kth = 0.0;
  #pragma unroll 1      // rolled: layer body fits I-cache
  for (int layer = 0; layer < 4; ++layer) {
    nrm = nrm * 0.7 + 1.0;            // w.sum(): 1, 1.7, 2.19, 2.533
    const double inv = 1.0 / nrm;

    // Deferred top-k + sparsity (f64), decay, recency recurrence.
    #pragma unroll
    for (int k = 0; k < 32; ++k) {
      double v = s_lds[k][tid];
      v = (fabs(v) >= thr) ? v : 0.0;
      ws[k] = ws[k] * 0.7 + v * 0.9;
    }

    // h = relu((ws @ Wenc^T)*inv + benc), f64 acc; weights are wave-uniform
    // SGPR pairs; 16 independent fma chains per k step.
    double hd[16];
    #pragma unroll
    for (int c = 0; c < 16; ++c) hd[c] = 0.0;
    #pragma unroll
    for (int k = 0; k < 32; ++k) {
      double wk = ws[k];
      #pragma unroll
      for (int c = 0; c < 16; ++c)
        hd[c] = fma(wk, g_wenc[c * 32 + k], hd[c]);
    }
    #pragma unroll
    for (int c = 0; c < 16; ++c)
      hd[c] = fmax(fma(hd[c], inv, g_benc[c]), 0.0);

    // Decoder (f64), importance threshold 0.05, write to LDS, fused
    // top-8 ladder (f64 -- compares must match the np f64 reference).
    double top[8];
    #pragma unroll
    for (int k = 0; k < 8; ++k) top[k] = 0.0;
    #pragma unroll
    for (int i = 0; i < 32; ++i) {
      double acc = g_bdec[i];
      #pragma unroll
      for (int c = 0; c < 16; ++c)
        acc = fma(hd[c], g_wdec[i * 16 + c], acc);
      double r = (fabs(acc) >= 0.05) ? acc : 0.0;
      s_lds[i][tid] = r;
      double v = fabs(r);
      #pragma unroll
      for (int k = 0; k < 8; ++k) {
        double hi = fmax(top[k], v);
        v = fmin(top[k], v);
        top[k] = hi;
      }
    }
    kth = top[7];                 // 8th largest of 32 (0 if <8 nonzero)
    thr = fmax(kth, 0.01);        // deferred into next layer's filter
  }

  // Final deferred top-k filter (layer 3's kth), convert, store.
  float4* dst = reinterpret_cast<float4*>(out + STATES_OFF) + (size_t)n * 8;
  #pragma unroll
  for (int j = 0; j < 8; ++j) {
    float r[4];
    #pragma unroll
    for (int q = 0; q < 4; ++q) {
      double v = s_lds[4 * j + q][tid];
      r[q] = (float)((fabs(v) >= kth) ? v : 0.0);
    }
    dst[j] = make_float4(r[0], r[1], r[2], r[3]);
  }
}

extern "C" void kernel_launch(void* const* d_in, const int* in_sizes, int n_in,
                              void* d_out, int out_size, void* d_ws, size_t ws_size,
                              hipStream_t stream) {
  const float* x    = (const float*)d_in[0];
  const float* ns   = (const float*)d_in[1];
  const float* Wenc = (const float*)d_in[2];
  const float* benc = (const float*)d_in[3];
  const float* Wdec = (const float*)d_in[4];
  const float* bdec = (const float*)d_in[5];
  float* out = (float*)d_out;

  convert_weights_kernel<<<1, 256, 0, stream>>>(Wenc, benc, Wdec, bdec);
  enn_states_kernel<<<N_NEURONS / 256, 256, 0, stream>>>(ns, out);
  tanh4_kernel<<<X4 / 256, 256, 0, stream>>>(x, out);
}

// Round 5
// 245.955 us; speedup vs baseline: 1.9969x; 1.1297x over previous
//
#include <hip/hip_runtime.h>

// Problem constants (fixed by reference)
constexpr int N_NEURONS  = 131072;
constexpr int X_ELEMS    = 4 * 131072 * 32;   // 16,777,216
constexpr int X4         = X_ELEMS / 4;       // 4,194,304 float4
constexpr int STATES_OFF = X_ELEMS;           // states start after x in d_out
constexpr int X4_PER_THR = X4 / N_NEURONS;    // 32 float4 per thread

// Fast tanh: t = 1 - 2/(e^{2|x|}+1), sign restored. Overflow-clean.
// Abs error ~1e-6 vs libm; passed all prior rounds.
__device__ __forceinline__ float fast_tanh(float x) {
  float a = fabsf(x);
  float e = __expf(2.0f * a);
  float t = 1.0f - __fdividef(2.0f, e + 1.0f);
  return copysignf(t, x);
}

// ---------------------------------------------------------------------------
// R9: single fused kernel (+ tiny weight-convert kernel).
//
// R8 post-mortem: spills fixed (WRITE = ideal), 133 µs, VALUBusy 62%.
// Fit: 320K cycles, 198K VALU-issue, ~26K instr/SIMD -> ~7.6 cyc/instr,
// consistent with f64 VALU at ~8 cyc/instr (wave64 DP pipe). Kernel is
// f64-issue-bound; f64 is pinned by correctness (R7 fail). Levers:
//  1. FUSE tanh path into this kernel: the f32 pipe + memory system idle
//     under the 8-cyc f64 shadow; 2 waves/SIMD issue tanh + loads into the
//     gaps. The separate 25 µs tanh dispatch should vanish into overlap.
//     8 float4-chunks per layer keeps the BW demand spread out.
//  2. Wenc transposed to [k][c] in convert kernel: encoder k-step reads 16
//     CONTIGUOUS doubles -> s_load_dwordx8 bursts instead of 16 strided
//     dwordx2 (SMEM issue + latency relief).
//  3. Dual interleaved top-8 ladders (even/odd i), merged exactly via
//     c[j]=max(a[j],b[7-j]) (top-8 of union, classic bitonic identity)
//     then kth = min-tree(c). Same op count, 2x ILP on the serial chain.
// Everything f64, decisions identical to R8 (which passed at bf16 quantum).
// ---------------------------------------------------------------------------

__device__ double g_wenc_t[32 * 16];  // TRANSPOSED: [k][c]
__device__ double g_wdec[32 * 16];    // [state][c] row-major, as given
__device__ double g_benc[16];
__device__ double g_bdec[32];

__global__ __launch_bounds__(256) void convert_weights_kernel(
    const float* __restrict__ Wenc, const float* __restrict__ benc,
    const float* __restrict__ Wdec, const float* __restrict__ bdec) {
  const int t = threadIdx.x;
  #pragma unroll
  for (int i = t; i < 512; i += 256) {
    const int k = i >> 4, c = i & 15;
    g_wenc_t[i] = (double)Wenc[c * 32 + k];   // transpose
    g_wdec[i]   = (double)Wdec[i];
  }
  if (t < 16)              g_benc[t]      = (double)benc[t];
  if (t >= 64 && t < 96)   g_bdec[t - 64] = (double)bdec[t - 64];
}

__global__ __launch_bounds__(256)
__attribute__((amdgpu_waves_per_eu(2, 2)))
void enn_fused_kernel(const float* __restrict__ x,
                      const float* __restrict__ ns,
                      float* __restrict__ out) {
  // 32 states x 256 threads, f64 = 64 KB. Column-per-thread: wave b64
  // access is 64 consecutive doubles -> conflict-free. No __syncthreads
  // needed (each thread touches only its own column).
  __shared__ double s_lds[32][256];

  const int tid = threadIdx.x;
  const int n   = blockIdx.x * 256 + tid;   // one neuron per thread

  const float4* src = reinterpret_cast<const float4*>(ns) + (size_t)n * 8;
  #pragma unroll
  for (int j = 0; j < 8; ++j) {
    float4 v = src[j];
    s_lds[4 * j + 0][tid] = (double)v.x;
    s_lds[4 * j + 1][tid] = (double)v.y;
    s_lds[4 * j + 2][tid] = (double)v.z;
    s_lds[4 * j + 3][tid] = (double)v.w;
  }

  double ws[32];
  #pragma unroll
  for (int i = 0; i < 32; ++i) ws[i] = 0.0;

  // x-path base: this thread's 32 float4, coalesced per chunk.
  const float4* xb = reinterpret_cast<const float4*>(x);
  float4*       ob = reinterpret_cast<float4*>(out);
  const size_t xbase = (size_t)blockIdx.x * (256 * X4_PER_THR) + tid;

  double nrm = 0.0;
  double thr = 0.01;    // layer-0: sparsity only (deferred kth = 0)
  double kth = 0.0;
  #pragma unroll 1      // rolled: layer body fits I-cache
  for (int layer = 0; layer < 4; ++layer) {
    // ---- fused tanh path: 8 float4 chunks this layer. f32 pipe + memory
    // ride under the f64 DP-pipe shadow (8 cyc/instr f64 leaves issue gaps).
    #pragma unroll
    for (int q = 0; q < 8; ++q) {
      const size_t idx = xbase + (size_t)(layer * 8 + q) * 256;
      float4 v = xb[idx];
      #pragma unroll
      for (int r = 0; r < 4; ++r) {   // tanh applied 4x (once per ref layer)
        v.x = fast_tanh(v.x);
        v.y = fast_tanh(v.y);
        v.z = fast_tanh(v.z);
        v.w = fast_tanh(v.w);
      }
      ob[idx] = v;
    }

    nrm = nrm * 0.7 + 1.0;            // w.sum(): 1, 1.7, 2.19, 2.533
    const double inv = 1.0 / nrm;

    // Deferred top-k + sparsity (f64), decay, recency recurrence.
    #pragma unroll
    for (int k = 0; k < 32; ++k) {
      double v = s_lds[k][tid];
      v = (fabs(v) >= thr) ? v : 0.0;
      ws[k] = ws[k] * 0.7 + v * 0.9;
    }

    // h = relu((ws @ Wenc^T)*inv + benc), f64 acc. Transposed weights:
    // each k-step reads 16 CONTIGUOUS doubles (wave-uniform -> SGPR burst).
    double hd[16];
    #pragma unroll
    for (int c = 0; c < 16; ++c) hd[c] = 0.0;
    #pragma unroll
    for (int k = 0; k < 32; ++k) {
      double wk = ws[k];
      #pragma unroll
      for (int c = 0; c < 16; ++c)
        hd[c] = fma(wk, g_wenc_t[k * 16 + c], hd[c]);
    }
    #pragma unroll
    for (int c = 0; c < 16; ++c)
      hd[c] = fmax(fma(hd[c], inv, g_benc[c]), 0.0);

    // Decoder (f64), importance threshold 0.05, write to LDS, dual
    // interleaved top-8 ladders (even/odd i) for 2x ILP on the serial chain.
    double ta[8], tb[8];
    #pragma unroll
    for (int k = 0; k < 8; ++k) { ta[k] = 0.0; tb[k] = 0.0; }
    #pragma unroll
    for (int i = 0; i < 32; ++i) {
      double acc = g_bdec[i];
      #pragma unroll
      for (int c = 0; c < 16; ++c)
        acc = fma(hd[c], g_wdec[i * 16 + c], acc);
      double r = (fabs(acc) >= 0.05) ? acc : 0.0;
      s_lds[i][tid] = r;
      double v = fabs(r);
      if ((i & 1) == 0) {
        #pragma unroll
        for (int k = 0; k < 8; ++k) {
          double hi = fmax(ta[k], v);
          v = fmin(ta[k], v);
          ta[k] = hi;
        }
      } else {
        #pragma unroll
        for (int k = 0; k < 8; ++k) {
          double hi = fmax(tb[k], v);
          v = fmin(tb[k], v);
          tb[k] = hi;
        }
      }
    }
    // top-8 of union of two sorted-desc 8-lists: c[j] = max(a[j], b[7-j]);
    // kth (8th largest overall) = min over c[].
    double m0 = fmax(ta[0], tb[7]), m1 = fmax(ta[1], tb[6]);
    double m2 = fmax(ta[2], tb[5]), m3 = fmax(ta[3], tb[4]);
    double m4 = fmax(ta[4], tb[3]), m5 = fmax(ta[5], tb[2]);
    double m6 = fmax(ta[6], tb[1]), m7 = fmax(ta[7], tb[0]);
    kth = fmin(fmin(fmin(m0, m1), fmin(m2, m3)),
               fmin(fmin(m4, m5), fmin(m6, m7)));
    thr = fmax(kth, 0.01);        // deferred into next layer's filter
  }

  // Final deferred top-k filter (layer 3's kth), convert, store.
  float4* dst = reinterpret_cast<float4*>(out + STATES_OFF) + (size_t)n * 8;
  #pragma unroll
  for (int j = 0; j < 8; ++j) {
    float r[4];
    #pragma unroll
    for (int q = 0; q < 4; ++q) {
      double v = s_lds[4 * j + q][tid];
      r[q] = (float)((fabs(v) >= kth) ? v : 0.0);
    }
    dst[j] = make_float4(r[0], r[1], r[2], r[3]);
  }
}

extern "C" void kernel_launch(void* const* d_in, const int* in_sizes, int n_in,
                              void* d_out, int out_size, void* d_ws, size_t ws_size,
                              hipStream_t stream) {
  const float* x    = (const float*)d_in[0];
  const float* ns   = (const float*)d_in[1];
  const float* Wenc = (const float*)d_in[2];
  const float* benc = (const float*)d_in[3];
  const float* Wdec = (const float*)d_in[4];
  const float* bdec = (const float*)d_in[5];
  float* out = (float*)d_out;

  convert_weights_kernel<<<1, 256, 0, stream>>>(Wenc, benc, Wdec, bdec);
  enn_fused_kernel<<<N_NEURONS / 256, 256, 0, stream>>>(x, ns, out);
}